// Round 1
// baseline (714.147 us; speedup 1.0000x reference)
//
#include <hip/hip_runtime.h>

// ---------------------------------------------------------------------------
// PathAttention block on MI355X. bf16 MFMA for all GEMM-shaped work.
// Needs ~175 MB of d_ws.
// ---------------------------------------------------------------------------

typedef __attribute__((ext_vector_type(4))) float f32x4;
typedef __attribute__((ext_vector_type(8))) short bf16x8;
typedef __attribute__((ext_vector_type(4))) short bf16x4;

#define MFMA(a, b, c) __builtin_amdgcn_mfma_f32_16x16x32_bf16(a, b, c, 0, 0, 0)

static __device__ __forceinline__ short f2bf(float x) {
  union { float f; unsigned u; } v; v.f = x;
  unsigned r = v.u + 0x7FFFu + ((v.u >> 16) & 1u);
  return (short)(r >> 16);
}
static __device__ __forceinline__ float bf2f(short b) {
  union { unsigned u; float f; } v;
  v.u = ((unsigned)(unsigned short)b) << 16;
  return v.f;
}

// ------------------------------ weight convert -----------------------------
__global__ void k_cvt(const float* __restrict__ s, short* __restrict__ d, int n) {
  int i = blockIdx.x * 256 + threadIdx.x;
  if (i < n) d[i] = f2bf(s[i]);
}

// ------------------------------ cnt histogram ------------------------------
__global__ void k_cnt(const int* __restrict__ pinv, float* __restrict__ cnt, int M) {
  int i = blockIdx.x * 256 + threadIdx.x;
  if (i < M) atomicAdd(&cnt[pinv[i]], 1.0f);
}

// --------------------- K1: LN(feat) -> qkv GEMM (bf16 out) -----------------
// block: 256 thr, 64 rows x 384 cols. LDS h tile swizzled, out staged for
// coalesced store.
__global__ __launch_bounds__(256) void k1_ln_qkv(
    const float* __restrict__ feat, const float* __restrict__ g1,
    const float* __restrict__ b1, const short* __restrict__ wq,
    const float* __restrict__ bq, short* __restrict__ qkvb) {
  __shared__ short h_lds[64 * 128];
  __shared__ short o_st[64 * 384];
  const int blk = blockIdx.x, t = threadIdx.x;
  {
    const int r = t >> 2, quad = t & 3;
    const float* fp = feat + (size_t)(blk * 64 + r) * 128 + quad * 32;
    float vals[32];
    float s = 0.f, s2 = 0.f;
#pragma unroll
    for (int i = 0; i < 8; i++) {
      f32x4 v = *(const f32x4*)(fp + i * 4);
#pragma unroll
      for (int j = 0; j < 4; j++) { float x = v[j]; vals[i * 4 + j] = x; s += x; s2 += x * x; }
    }
    s += __shfl_xor(s, 1);  s += __shfl_xor(s, 2);
    s2 += __shfl_xor(s2, 1); s2 += __shfl_xor(s2, 2);
    float mean = s * (1.f / 128.f);
    float rstd = rsqrtf(s2 * (1.f / 128.f) - mean * mean + 1e-5f);
    const int sw = (r & 7) << 4;
#pragma unroll
    for (int gi = 0; gi < 4; gi++) {
      bf16x8 wv;
#pragma unroll
      for (int j = 0; j < 8; j++) {
        int c = quad * 32 + gi * 8 + j;
        wv[j] = f2bf((vals[gi * 8 + j] - mean) * rstd * g1[c] + b1[c]);
      }
      *(bf16x8*)((char*)h_lds + r * 256 + ((quad * 64 + gi * 16) ^ sw)) = wv;
    }
  }
  __syncthreads();
  const int wave = t >> 6, lane = t & 63, u = lane & 15, g = lane >> 4;
  f32x4 acc[4][6];
  f32x4 zz = {0.f, 0.f, 0.f, 0.f};
#pragma unroll
  for (int a = 0; a < 4; a++)
#pragma unroll
    for (int b = 0; b < 6; b++) acc[a][b] = zz;
#pragma unroll
  for (int kk = 0; kk < 4; kk++) {
    bf16x8 af[4];
#pragma unroll
    for (int rt = 0; rt < 4; rt++)
      af[rt] = *(const bf16x8*)((char*)h_lds + (rt * 16 + u) * 256 +
                                ((kk * 64 + g * 16) ^ ((u & 7) << 4)));
    bf16x8 bfr[6];
#pragma unroll
    for (int ct = 0; ct < 6; ct++) {
      int col = wave * 96 + ct * 16 + u;
      bfr[ct] = *(const bf16x8*)(wq + (size_t)col * 128 + kk * 32 + g * 8);
    }
#pragma unroll
    for (int rt = 0; rt < 4; rt++)
#pragma unroll
      for (int ct = 0; ct < 6; ct++) acc[rt][ct] = MFMA(af[rt], bfr[ct], acc[rt][ct]);
  }
#pragma unroll
  for (int rt = 0; rt < 4; rt++)
#pragma unroll
    for (int ct = 0; ct < 6; ct++) {
      int col = wave * 96 + ct * 16 + u;
      float bias = bq[col];
#pragma unroll
      for (int reg = 0; reg < 4; reg++) {
        int rowl = rt * 16 + 4 * g + reg;
        o_st[rowl * 384 + col] = f2bf(acc[rt][ct][reg] + bias);
      }
    }
  __syncthreads();
  for (int idx = t; idx < 3072; idx += 256) {
    int rr = idx / 48, c8 = idx % 48;
    *(bf16x8*)(qkvb + ((size_t)blk * 64 + rr) * 384 + c8 * 8) =
        *(const bf16x8*)(o_st + rr * 384 + c8 * 8);
  }
}

// --------------------- K2: windowed attention per 48-block -----------------
// block: 512 thr (8 waves = 8 heads). Gather+RoPE stage -> swapped QK^T mfma
// -> in-register softmax -> PV mfma (V staged transposed) -> write canonical
// rows compacted by m.
__global__ __launch_bounds__(512) void k2_attn(
    const short* __restrict__ qkv, const float* __restrict__ cosb,
    const float* __restrict__ sinb, const int* __restrict__ pinv,
    const int* __restrict__ padv, const int* __restrict__ unpadv,
    short* __restrict__ ocmp) {
  __shared__ short q_lds[48 * 128];
  __shared__ short k_lds[48 * 128];
  __shared__ short vT[8 * 16 * 64];  // [h][d][j], j padded to 64
  __shared__ short o_lds[48 * 128];
  __shared__ int midx_s[48];
  __shared__ int gidx_s[48];
  __shared__ int canon_s[48];
  __shared__ float cs_s[48 * 8];
  __shared__ float sn_s[48 * 8];

  const int w = blockIdx.x;
  const int t = threadIdx.x;

  if (t < 48) {
    int pp = w * 48 + t;
    int m = padv[pp];
    midx_s[t] = m;
    gidx_s[t] = pinv[m];
    canon_s[t] = (unpadv[m] == pp) ? 1 : 0;
    const float* cp = cosb + (size_t)m * 16;
    const float* sp = sinb + (size_t)m * 16;
#pragma unroll
    for (int i = 0; i < 2; i++) {
      *(f32x4*)(cs_s + t * 8 + i * 4) = *(const f32x4*)(cp + i * 4);
      *(f32x4*)(sn_s + t * 8 + i * 4) = *(const f32x4*)(sp + i * 4);
    }
  }
  __syncthreads();

  {  // stage qkv rows with RoPE; V goes in transposed
    const int r = t >> 3, seg = t & 7;
    if (r < 48) {
      const short* rowp = qkv + (size_t)gidx_s[r] * 384;
#pragma unroll
      for (int ci = 0; ci < 3; ci++) {
        const int c0 = seg * 48 + ci * 16;
        const int sec = c0 >> 7;
        const int hh = (c0 & 127) >> 4;
        bf16x8 lo = *(const bf16x8*)(rowp + c0);
        bf16x8 hi = *(const bf16x8*)(rowp + c0 + 8);
        if (sec < 2) {
          bf16x8 w0, w1;
#pragma unroll
          for (int j = 0; j < 8; j++) {
            float x1 = bf2f(lo[j]), x2 = bf2f(hi[j]);
            float cp = cs_s[r * 8 + j], sp2 = sn_s[r * 8 + j];
            w0[j] = f2bf(x1 * cp - x2 * sp2);
            w1[j] = f2bf(x2 * cp + x1 * sp2);
          }
          char* dst = (char*)(sec == 0 ? q_lds : k_lds);
          int sw = (r & 7) << 4;
          *(bf16x8*)(dst + r * 256 + ((hh * 32) ^ sw)) = w0;
          *(bf16x8*)(dst + r * 256 + ((hh * 32 + 16) ^ sw)) = w1;
        } else {
#pragma unroll
          for (int d = 0; d < 16; d++) {
            short val = (d < 8) ? lo[d] : hi[d - 8];
            *(short*)((char*)vT + hh * 2048 + d * 128 + ((r * 2) ^ ((d & 7) << 3))) = val;
          }
        }
      }
    } else {  // r in 48..63: zero the V j-padding
#pragma unroll
      for (int ci = 0; ci < 3; ci++) {
        const int c0 = seg * 48 + ci * 16;
        if (c0 >= 256) {
          const int hh = (c0 & 127) >> 4;
#pragma unroll
          for (int d = 0; d < 16; d++)
            *(short*)((char*)vT + hh * 2048 + d * 128 + ((r * 2) ^ ((d & 7) << 3))) = 0;
        }
      }
    }
  }
  __syncthreads();

  const int h = t >> 6, lane = t & 63, u = lane & 15, g = lane >> 4;
  const int sbase = h * 32 + g * 16;
  bf16x8 zf = {0, 0, 0, 0, 0, 0, 0, 0};
  bf16x8 kf[3], qf[3];
#pragma unroll
  for (int i = 0; i < 3; i++) {
    int kj = i * 16 + u;
    if (g < 2) {
      kf[i] = *(const bf16x8*)((char*)k_lds + kj * 256 + (sbase ^ ((kj & 7) << 4)));
      qf[i] = *(const bf16x8*)((char*)q_lds + kj * 256 + (sbase ^ ((kj & 7) << 4)));
    } else { kf[i] = zf; qf[i] = zf; }
  }
  f32x4 d1[3][3];
#pragma unroll
  for (int a = 0; a < 3; a++)
#pragma unroll
    for (int b = 0; b < 3; b++) {
      f32x4 z = {0.f, 0.f, 0.f, 0.f};
      d1[a][b] = MFMA(kf[a], qf[b], z);  // D1[kj][q] (scores^T)
    }

  float rl[3];
#pragma unroll
  for (int qt = 0; qt < 3; qt++) {
    float mx = -3.0e38f;
#pragma unroll
    for (int kt = 0; kt < 3; kt++)
#pragma unroll
      for (int rr = 0; rr < 4; rr++) {
        float sv = d1[kt][qt][rr] * 0.25f;
        d1[kt][qt][rr] = sv;
        mx = fmaxf(mx, sv);
      }
    mx = fmaxf(mx, __shfl_xor(mx, 16));
    mx = fmaxf(mx, __shfl_xor(mx, 32));
    float sm = 0.f;
#pragma unroll
    for (int kt = 0; kt < 3; kt++)
#pragma unroll
      for (int rr = 0; rr < 4; rr++) {
        float e = __expf(d1[kt][qt][rr] - mx);
        d1[kt][qt][rr] = e;
        sm += e;
      }
    sm += __shfl_xor(sm, 16);
    sm += __shfl_xor(sm, 32);
    rl[qt] = 1.0f / sm;
  }

  union UU { bf16x8 v8; bf16x4 v4[2]; };
  UU a1, a2;
  {
    const int dbase = h * 2048 + u * 128;
    const int sw = (u & 7) << 3;
    a1.v4[0] = *(const bf16x4*)((char*)vT + dbase + ((8 * g) ^ sw));
    a1.v4[1] = *(const bf16x4*)((char*)vT + dbase + ((32 + 8 * g) ^ sw));
    a2.v4[0] = *(const bf16x4*)((char*)vT + dbase + ((64 + 8 * g) ^ sw));
    a2.v4[1] = *(const bf16x4*)((char*)vT + dbase + ((96 + 8 * g) ^ sw));
  }
#pragma unroll
  for (int qt = 0; qt < 3; qt++) {
    UU bu1, bu2;
#pragma unroll
    for (int i = 0; i < 4; i++) {
      bu1.v8[i] = f2bf(d1[0][qt][i]);
      bu1.v8[i + 4] = f2bf(d1[1][qt][i]);
      bu2.v8[i] = f2bf(d1[2][qt][i]);
      bu2.v8[i + 4] = 0;
    }
    f32x4 z = {0.f, 0.f, 0.f, 0.f};
    f32x4 acc = MFMA(a1.v8, bu1.v8, z);
    acc = MFMA(a2.v8, bu2.v8, acc);  // o^T[d][q]
#pragma unroll
    for (int reg = 0; reg < 4; reg++)
      o_lds[(qt * 16 + u) * 128 + h * 16 + 4 * g + reg] = f2bf(acc[reg] * rl[qt]);
  }
  __syncthreads();
  for (int idx = t; idx < 768; idx += 512) {
    int r = idx >> 4, c8 = idx & 15;
    if (canon_s[r]) {
      *(bf16x8*)(ocmp + (size_t)midx_s[r] * 128 + c8 * 8) =
          *(const bf16x8*)(o_lds + r * 128 + c8 * 8);
    }
  }
}

// --------------------- K3: proj GEMM + atomic segment-sum ------------------
__global__ __launch_bounds__(256) void k3_proj(
    const short* __restrict__ ocmp, const short* __restrict__ wp,
    const float* __restrict__ pb, const int* __restrict__ pinv,
    float* __restrict__ dout, int M) {
  __shared__ short a_lds[64 * 128];
  __shared__ int nidx[64];
  const int blk = blockIdx.x, t = threadIdx.x;
  const int m0 = blk * 64;
  {
    const int r = t >> 2, quad = t & 3;
    const int m = m0 + r;
    if (quad == 0) nidx[r] = (m < M) ? pinv[m] : 0;
    if (m < M) {
      const char* src = (const char*)(ocmp + (size_t)m * 128);
#pragma unroll
      for (int i = 0; i < 4; i++) {
        int boff = quad * 64 + i * 16;
        *(bf16x8*)((char*)a_lds + r * 256 + (boff ^ ((r & 7) << 4))) =
            *(const bf16x8*)(src + boff);
      }
    } else {
      bf16x8 z = {0, 0, 0, 0, 0, 0, 0, 0};
#pragma unroll
      for (int i = 0; i < 4; i++) {
        int boff = quad * 64 + i * 16;
        *(bf16x8*)((char*)a_lds + r * 256 + (boff ^ ((r & 7) << 4))) = z;
      }
    }
  }
  __syncthreads();
  const int wave = t >> 6, lane = t & 63, u = lane & 15, g = lane >> 4;
  f32x4 acc[4][2];
  f32x4 zz = {0.f, 0.f, 0.f, 0.f};
#pragma unroll
  for (int a = 0; a < 4; a++) { acc[a][0] = zz; acc[a][1] = zz; }
#pragma unroll
  for (int kk = 0; kk < 4; kk++) {
    bf16x8 af[4];
#pragma unroll
    for (int rt = 0; rt < 4; rt++)
      af[rt] = *(const bf16x8*)((char*)a_lds + (rt * 16 + u) * 256 +
                                ((kk * 64 + g * 16) ^ ((u & 7) << 4)));
    bf16x8 bfr[2];
#pragma unroll
    for (int ct = 0; ct < 2; ct++) {
      int col = wave * 32 + ct * 16 + u;
      bfr[ct] = *(const bf16x8*)(wp + (size_t)col * 128 + kk * 32 + g * 8);
    }
#pragma unroll
    for (int rt = 0; rt < 4; rt++)
#pragma unroll
      for (int ct = 0; ct < 2; ct++) acc[rt][ct] = MFMA(af[rt], bfr[ct], acc[rt][ct]);
  }
#pragma unroll
  for (int rt = 0; rt < 4; rt++)
#pragma unroll
    for (int ct = 0; ct < 2; ct++) {
      int col = wave * 32 + ct * 16 + u;
      float bias = pb[col];
#pragma unroll
      for (int reg = 0; reg < 4; reg++) {
        int ml = rt * 16 + 4 * g + reg;
        if (m0 + ml < M)
          atomicAdd(dout + (size_t)nidx[ml] * 128 + col, acc[rt][ct][reg] + bias);
      }
    }
}

// ------- K4b: x = feat + sums/cnt (in-place in d_out); LN2; fc1+GELU -------
__global__ __launch_bounds__(256) void k4b_x_ln_fc1(
    const float* __restrict__ feat, float* __restrict__ dout,
    const float* __restrict__ cnt, const float* __restrict__ g2,
    const float* __restrict__ b2, const short* __restrict__ w1,
    const float* __restrict__ bb1, short* __restrict__ mact) {
  __shared__ short h_lds[64 * 128];
  __shared__ short o_st[64 * 512];
  const int blk = blockIdx.x, t = threadIdx.x;
  {
    const int r = t >> 2, quad = t & 3;
    const size_t row = (size_t)blk * 64 + r;
    const float* fp = feat + row * 128 + quad * 32;
    float* xp = dout + row * 128 + quad * 32;
    float rc = 1.0f / fmaxf(cnt[row], 1.0f);
    float vals[32];
    float s = 0.f, s2 = 0.f;
#pragma unroll
    for (int i = 0; i < 8; i++) {
      f32x4 fv = *(const f32x4*)(fp + i * 4);
      f32x4 sv = *(const f32x4*)(xp + i * 4);
      f32x4 xv;
#pragma unroll
      for (int j = 0; j < 4; j++) {
        float x = fv[j] + sv[j] * rc;
        xv[j] = x; vals[i * 4 + j] = x; s += x; s2 += x * x;
      }
      *(f32x4*)(xp + i * 4) = xv;
    }
    s += __shfl_xor(s, 1);  s += __shfl_xor(s, 2);
    s2 += __shfl_xor(s2, 1); s2 += __shfl_xor(s2, 2);
    float mean = s * (1.f / 128.f);
    float rstd = rsqrtf(s2 * (1.f / 128.f) - mean * mean + 1e-5f);
    const int sw = (r & 7) << 4;
#pragma unroll
    for (int gi = 0; gi < 4; gi++) {
      bf16x8 wv;
#pragma unroll
      for (int j = 0; j < 8; j++) {
        int c = quad * 32 + gi * 8 + j;
        wv[j] = f2bf((vals[gi * 8 + j] - mean) * rstd * g2[c] + b2[c]);
      }
      *(bf16x8*)((char*)h_lds + r * 256 + ((quad * 64 + gi * 16) ^ sw)) = wv;
    }
  }
  __syncthreads();
  const int wave = t >> 6, lane = t & 63, u = lane & 15, g = lane >> 4;
  f32x4 acc[4][8];
  f32x4 zz = {0.f, 0.f, 0.f, 0.f};
#pragma unroll
  for (int a = 0; a < 4; a++)
#pragma unroll
    for (int b = 0; b < 8; b++) acc[a][b] = zz;
#pragma unroll
  for (int kk = 0; kk < 4; kk++) {
    bf16x8 af[4];
#pragma unroll
    for (int rt = 0; rt < 4; rt++)
      af[rt] = *(const bf16x8*)((char*)h_lds + (rt * 16 + u) * 256 +
                                ((kk * 64 + g * 16) ^ ((u & 7) << 4)));
    bf16x8 bfr[8];
#pragma unroll
    for (int ct = 0; ct < 8; ct++) {
      int col = wave * 128 + ct * 16 + u;
      bfr[ct] = *(const bf16x8*)(w1 + (size_t)col * 128 + kk * 32 + g * 8);
    }
#pragma unroll
    for (int rt = 0; rt < 4; rt++)
#pragma unroll
      for (int ct = 0; ct < 8; ct++) acc[rt][ct] = MFMA(af[rt], bfr[ct], acc[rt][ct]);
  }
#pragma unroll
  for (int rt = 0; rt < 4; rt++)
#pragma unroll
    for (int ct = 0; ct < 8; ct++) {
      int col = wave * 128 + ct * 16 + u;
      float bias = bb1[col];
#pragma unroll
      for (int reg = 0; reg < 4; reg++) {
        int rowl = rt * 16 + 4 * g + reg;
        float v = acc[rt][ct][reg] + bias;
        v = 0.5f * v * (1.0f + erff(v * 0.70710678118654752f));  // exact GELU
        o_st[rowl * 512 + col] = f2bf(v);
      }
    }
  __syncthreads();
  for (int idx = t; idx < 4096; idx += 256) {
    int rr = idx >> 6, c8 = idx & 63;
    *(bf16x8*)(mact + ((size_t)blk * 64 + rr) * 512 + c8 * 8) =
        *(const bf16x8*)(o_st + rr * 512 + c8 * 8);
  }
}

// --------------------- K4c: fc2 + residual into d_out ----------------------
__global__ __launch_bounds__(256) void k4c_fc2(
    const short* __restrict__ mact, const short* __restrict__ w2,
    const float* __restrict__ bb2, float* __restrict__ dout) {
  __shared__ short a_lds[64 * 512];
  const int blk = blockIdx.x, t = threadIdx.x;
  {
    const int r = t >> 2, quad = t & 3;
    const size_t row = (size_t)blk * 64 + r;
    const char* src = (const char*)(mact + row * 512);
#pragma unroll
    for (int i = 0; i < 16; i++) {
      int boff = quad * 256 + i * 16;
      *(bf16x8*)((char*)a_lds + r * 1024 + (boff ^ ((r & 7) << 4))) =
          *(const bf16x8*)(src + boff);
    }
  }
  __syncthreads();
  const int wave = t >> 6, lane = t & 63, u = lane & 15, g = lane >> 4;
  f32x4 acc[8];
  f32x4 zz = {0.f, 0.f, 0.f, 0.f};
#pragma unroll
  for (int a = 0; a < 8; a++) acc[a] = zz;
  const int rowl = wave * 16 + u;
#pragma unroll
  for (int kk = 0; kk < 16; kk++) {
    bf16x8 af = *(const bf16x8*)((char*)a_lds + rowl * 1024 +
                                 ((kk * 64 + g * 16) ^ ((u & 7) << 4)));
#pragma unroll
    for (int ct = 0; ct < 8; ct++) {
      int col = ct * 16 + u;
      bf16x8 bfr = *(const bf16x8*)(w2 + (size_t)col * 512 + kk * 32 + g * 8);
      acc[ct] = MFMA(af, bfr, acc[ct]);
    }
  }
#pragma unroll
  for (int ct = 0; ct < 8; ct++) {
    int col = ct * 16 + u;
    float bias = bb2[col];
#pragma unroll
    for (int reg = 0; reg < 4; reg++) {
      size_t rr = (size_t)blk * 64 + wave * 16 + 4 * g + reg;
      float* p = dout + rr * 128 + col;
      *p = *p + acc[ct][reg] + bias;
    }
  }
}

// ---------------------------------------------------------------------------
extern "C" void kernel_launch(void* const* d_in, const int* in_sizes, int n_in,
                              void* d_out, int out_size, void* d_ws, size_t ws_size,
                              hipStream_t stream) {
  (void)n_in; (void)out_size; (void)ws_size;
  const float* feat   = (const float*)d_in[0];
  const float* cosb   = (const float*)d_in[1];
  const float* sinb   = (const float*)d_in[2];
  const float* g1     = (const float*)d_in[3];
  const float* b1     = (const float*)d_in[4];
  const float* qkv_w  = (const float*)d_in[5];
  const float* qkv_b  = (const float*)d_in[6];
  const float* proj_w = (const float*)d_in[7];
  const float* proj_b = (const float*)d_in[8];
  const float* g2     = (const float*)d_in[9];
  const float* b2     = (const float*)d_in[10];
  const float* fc1_w  = (const float*)d_in[11];
  const float* fc1_b  = (const float*)d_in[12];
  const float* fc2_w  = (const float*)d_in[13];
  const float* fc2_b  = (const float*)d_in[14];
  const int* pinv     = (const int*)d_in[15];
  const int* padv     = (const int*)d_in[16];
  const int* unpadv   = (const int*)d_in[17];

  const int N    = in_sizes[0] / 128;
  const int M    = in_sizes[15];
  const int Mpad = in_sizes[16];
  const int Wn   = Mpad / 48;

  float* dout = (float*)d_out;
  char* ws = (char*)d_ws;

  // ws layout (bytes):
  //  [0, N*384*2)                      qkv bf16        (dead after K2)
  //  [N*384*2, +M*128*2)               o_cmp bf16      (dead after K3)
  //  [0, N*512*2)                      mact bf16       (reuses qkv+ocmp space)
  //  then cnt (N*4), then bf16 weights (393216 B). Total ~175 MB.
  size_t offQ = 0;
  size_t szQ = (size_t)N * 384 * 2;
  size_t offO = offQ + szQ;
  size_t szO = (size_t)M * 128 * 2;
  size_t offC = offO + szO;
  size_t offW = offC + (size_t)N * 4;

  short* qkvb = (short*)(ws + offQ);
  short* ocmp = (short*)(ws + offO);
  short* mact = (short*)(ws + offQ);  // overlaps qkv/ocmp (both dead by K4b)
  float* cnt  = (float*)(ws + offC);
  short* wq_b = (short*)(ws + offW);
  short* wp_b = wq_b + 49152;
  short* w1_b = wp_b + 16384;
  short* w2_b = w1_b + 65536;

  hipMemsetAsync(dout, 0, (size_t)N * 128 * 4, stream);
  hipMemsetAsync(cnt, 0, (size_t)N * 4, stream);

  k_cvt<<<(49152 + 255) / 256, 256, 0, stream>>>(qkv_w, wq_b, 49152);
  k_cvt<<<(16384 + 255) / 256, 256, 0, stream>>>(proj_w, wp_b, 16384);
  k_cvt<<<(65536 + 255) / 256, 256, 0, stream>>>(fc1_w, w1_b, 65536);
  k_cvt<<<(65536 + 255) / 256, 256, 0, stream>>>(fc2_w, w2_b, 65536);

  k1_ln_qkv<<<N / 64, 256, 0, stream>>>(feat, g1, b1, wq_b, qkv_b, qkvb);
  k_cnt<<<(M + 255) / 256, 256, 0, stream>>>(pinv, cnt, M);
  k2_attn<<<Wn, 512, 0, stream>>>(qkvb, cosb, sinb, pinv, padv, unpadv, ocmp);
  k3_proj<<<(M + 63) / 64, 256, 0, stream>>>(ocmp, wp_b, proj_b, pinv, dout, M);
  k4b_x_ln_fc1<<<N / 64, 256, 0, stream>>>(feat, dout, cnt, g2, b2, w1_b, fc1_b, mact);
  k4c_fc2<<<N / 64, 256, 0, stream>>>(mact, w2_b, fc2_b, dout);
}

// Round 2
// 713.672 us; speedup vs baseline: 1.0007x; 1.0007x over previous
//
#include <hip/hip_runtime.h>

// ---------------------------------------------------------------------------
// PathAttention block on MI355X. bf16 MFMA for all GEMM-shaped work.
// Needs ~175 MB of d_ws.
// ---------------------------------------------------------------------------

typedef __attribute__((ext_vector_type(4))) float f32x4;
typedef __attribute__((ext_vector_type(8))) short bf16x8;
typedef __attribute__((ext_vector_type(4))) short bf16x4;

#define MFMA(a, b, c) __builtin_amdgcn_mfma_f32_16x16x32_bf16(a, b, c, 0, 0, 0)

static __device__ __forceinline__ short f2bf(float x) {
  union { float f; unsigned u; } v; v.f = x;
  unsigned r = v.u + 0x7FFFu + ((v.u >> 16) & 1u);
  return (short)(r >> 16);
}
static __device__ __forceinline__ float bf2f(short b) {
  union { unsigned u; float f; } v;
  v.u = ((unsigned)(unsigned short)b) << 16;
  return v.f;
}

// ------------------------------ weight convert -----------------------------
__global__ void k_cvt(const float* __restrict__ s, short* __restrict__ d, int n) {
  int i = blockIdx.x * 256 + threadIdx.x;
  if (i < n) d[i] = f2bf(s[i]);
}

// ------------------------------ cnt histogram ------------------------------
__global__ void k_cnt(const int* __restrict__ pinv, float* __restrict__ cnt, int M) {
  int i = blockIdx.x * 256 + threadIdx.x;
  if (i < M) atomicAdd(&cnt[pinv[i]], 1.0f);
}

// --------------------- K1: LN(feat) -> qkv GEMM (bf16 out) -----------------
// block: 256 thr, 64 rows x 384 cols. LDS h tile swizzled, out staged for
// coalesced store.
__global__ __launch_bounds__(256) void k1_ln_qkv(
    const float* __restrict__ feat, const float* __restrict__ g1,
    const float* __restrict__ b1, const short* __restrict__ wq,
    const float* __restrict__ bq, short* __restrict__ qkvb) {
  __shared__ short h_lds[64 * 128];
  __shared__ short o_st[64 * 384];
  const int blk = blockIdx.x, t = threadIdx.x;
  {
    const int r = t >> 2, quad = t & 3;
    const float* fp = feat + (size_t)(blk * 64 + r) * 128 + quad * 32;
    float vals[32];
    float s = 0.f, s2 = 0.f;
#pragma unroll
    for (int i = 0; i < 8; i++) {
      f32x4 v = *(const f32x4*)(fp + i * 4);
#pragma unroll
      for (int j = 0; j < 4; j++) { float x = v[j]; vals[i * 4 + j] = x; s += x; s2 += x * x; }
    }
    s += __shfl_xor(s, 1);  s += __shfl_xor(s, 2);
    s2 += __shfl_xor(s2, 1); s2 += __shfl_xor(s2, 2);
    float mean = s * (1.f / 128.f);
    float rstd = rsqrtf(s2 * (1.f / 128.f) - mean * mean + 1e-5f);
    const int sw = (r & 7) << 4;
#pragma unroll
    for (int gi = 0; gi < 4; gi++) {
      bf16x8 wv;
#pragma unroll
      for (int j = 0; j < 8; j++) {
        int c = quad * 32 + gi * 8 + j;
        wv[j] = f2bf((vals[gi * 8 + j] - mean) * rstd * g1[c] + b1[c]);
      }
      *(bf16x8*)((char*)h_lds + r * 256 + ((quad * 64 + gi * 16) ^ sw)) = wv;
    }
  }
  __syncthreads();
  const int wave = t >> 6, lane = t & 63, u = lane & 15, g = lane >> 4;
  f32x4 acc[4][6];
  f32x4 zz = {0.f, 0.f, 0.f, 0.f};
#pragma unroll
  for (int a = 0; a < 4; a++)
#pragma unroll
    for (int b = 0; b < 6; b++) acc[a][b] = zz;
#pragma unroll
  for (int kk = 0; kk < 4; kk++) {
    bf16x8 af[4];
#pragma unroll
    for (int rt = 0; rt < 4; rt++)
      af[rt] = *(const bf16x8*)((char*)h_lds + (rt * 16 + u) * 256 +
                                ((kk * 64 + g * 16) ^ ((u & 7) << 4)));
    bf16x8 bfr[6];
#pragma unroll
    for (int ct = 0; ct < 6; ct++) {
      int col = wave * 96 + ct * 16 + u;
      bfr[ct] = *(const bf16x8*)(wq + (size_t)col * 128 + kk * 32 + g * 8);
    }
#pragma unroll
    for (int rt = 0; rt < 4; rt++)
#pragma unroll
      for (int ct = 0; ct < 6; ct++) acc[rt][ct] = MFMA(af[rt], bfr[ct], acc[rt][ct]);
  }
#pragma unroll
  for (int rt = 0; rt < 4; rt++)
#pragma unroll
    for (int ct = 0; ct < 6; ct++) {
      int col = wave * 96 + ct * 16 + u;
      float bias = bq[col];
#pragma unroll
      for (int reg = 0; reg < 4; reg++) {
        int rowl = rt * 16 + 4 * g + reg;
        o_st[rowl * 384 + col] = f2bf(acc[rt][ct][reg] + bias);
      }
    }
  __syncthreads();
  for (int idx = t; idx < 3072; idx += 256) {
    int rr = idx / 48, c8 = idx % 48;
    *(bf16x8*)(qkvb + ((size_t)blk * 64 + rr) * 384 + c8 * 8) =
        *(const bf16x8*)(o_st + rr * 384 + c8 * 8);
  }
}

// --------------------- K2: windowed attention per 48-block -----------------
// block: 512 thr (8 waves = 8 heads). Gather+RoPE stage -> swapped QK^T mfma
// -> in-register softmax -> PV mfma (V staged transposed) -> write canonical
// rows compacted by m.
__global__ __launch_bounds__(512) void k2_attn(
    const short* __restrict__ qkv, const float* __restrict__ cosb,
    const float* __restrict__ sinb, const int* __restrict__ pinv,
    const int* __restrict__ padv, const int* __restrict__ unpadv,
    short* __restrict__ ocmp) {
  __shared__ short q_lds[48 * 128];
  __shared__ short k_lds[48 * 128];
  __shared__ short vT[8 * 16 * 64];  // [h][d][j], j padded to 64
  __shared__ short o_lds[48 * 128];
  __shared__ int midx_s[48];
  __shared__ int gidx_s[48];
  __shared__ int canon_s[48];
  __shared__ float cs_s[48 * 8];
  __shared__ float sn_s[48 * 8];

  const int w = blockIdx.x;
  const int t = threadIdx.x;

  if (t < 48) {
    int pp = w * 48 + t;
    int m = padv[pp];
    midx_s[t] = m;
    gidx_s[t] = pinv[m];
    canon_s[t] = (unpadv[m] == pp) ? 1 : 0;
    const float* cp = cosb + (size_t)m * 16;
    const float* sp = sinb + (size_t)m * 16;
#pragma unroll
    for (int i = 0; i < 2; i++) {
      *(f32x4*)(cs_s + t * 8 + i * 4) = *(const f32x4*)(cp + i * 4);
      *(f32x4*)(sn_s + t * 8 + i * 4) = *(const f32x4*)(sp + i * 4);
    }
  }
  __syncthreads();

  {  // stage qkv rows with RoPE; V goes in transposed
    const int r = t >> 3, seg = t & 7;
    if (r < 48) {
      const short* rowp = qkv + (size_t)gidx_s[r] * 384;
#pragma unroll
      for (int ci = 0; ci < 3; ci++) {
        const int c0 = seg * 48 + ci * 16;
        const int sec = c0 >> 7;
        const int hh = (c0 & 127) >> 4;
        bf16x8 lo = *(const bf16x8*)(rowp + c0);
        bf16x8 hi = *(const bf16x8*)(rowp + c0 + 8);
        if (sec < 2) {
          bf16x8 w0, w1;
#pragma unroll
          for (int j = 0; j < 8; j++) {
            float x1 = bf2f(lo[j]), x2 = bf2f(hi[j]);
            float cp = cs_s[r * 8 + j], sp2 = sn_s[r * 8 + j];
            w0[j] = f2bf(x1 * cp - x2 * sp2);
            w1[j] = f2bf(x2 * cp + x1 * sp2);
          }
          char* dst = (char*)(sec == 0 ? q_lds : k_lds);
          int sw = (r & 7) << 4;
          *(bf16x8*)(dst + r * 256 + ((hh * 32) ^ sw)) = w0;
          *(bf16x8*)(dst + r * 256 + ((hh * 32 + 16) ^ sw)) = w1;
        } else {
#pragma unroll
          for (int d = 0; d < 16; d++) {
            short val = (d < 8) ? lo[d] : hi[d - 8];
            *(short*)((char*)vT + hh * 2048 + d * 128 + ((r * 2) ^ ((d & 7) << 3))) = val;
          }
        }
      }
    } else {  // r in 48..63: zero the V j-padding
#pragma unroll
      for (int ci = 0; ci < 3; ci++) {
        const int c0 = seg * 48 + ci * 16;
        if (c0 >= 256) {
          const int hh = (c0 & 127) >> 4;
#pragma unroll
          for (int d = 0; d < 16; d++)
            *(short*)((char*)vT + hh * 2048 + d * 128 + ((r * 2) ^ ((d & 7) << 3))) = 0;
        }
      }
    }
  }
  __syncthreads();

  const int h = t >> 6, lane = t & 63, u = lane & 15, g = lane >> 4;
  const int sbase = h * 32 + g * 16;
  bf16x8 zf = {0, 0, 0, 0, 0, 0, 0, 0};
  bf16x8 kf[3], qf[3];
#pragma unroll
  for (int i = 0; i < 3; i++) {
    int kj = i * 16 + u;
    if (g < 2) {
      kf[i] = *(const bf16x8*)((char*)k_lds + kj * 256 + (sbase ^ ((kj & 7) << 4)));
      qf[i] = *(const bf16x8*)((char*)q_lds + kj * 256 + (sbase ^ ((kj & 7) << 4)));
    } else { kf[i] = zf; qf[i] = zf; }
  }
  f32x4 d1[3][3];
#pragma unroll
  for (int a = 0; a < 3; a++)
#pragma unroll
    for (int b = 0; b < 3; b++) {
      f32x4 z = {0.f, 0.f, 0.f, 0.f};
      d1[a][b] = MFMA(kf[a], qf[b], z);  // D1[kj][q] (scores^T)
    }

  float rl[3];
#pragma unroll
  for (int qt = 0; qt < 3; qt++) {
    float mx = -3.0e38f;
#pragma unroll
    for (int kt = 0; kt < 3; kt++)
#pragma unroll
      for (int rr = 0; rr < 4; rr++) {
        float sv = d1[kt][qt][rr] * 0.25f;
        d1[kt][qt][rr] = sv;
        mx = fmaxf(mx, sv);
      }
    mx = fmaxf(mx, __shfl_xor(mx, 16));
    mx = fmaxf(mx, __shfl_xor(mx, 32));
    float sm = 0.f;
#pragma unroll
    for (int kt = 0; kt < 3; kt++)
#pragma unroll
      for (int rr = 0; rr < 4; rr++) {
        float e = __expf(d1[kt][qt][rr] - mx);
        d1[kt][qt][rr] = e;
        sm += e;
      }
    sm += __shfl_xor(sm, 16);
    sm += __shfl_xor(sm, 32);
    rl[qt] = 1.0f / sm;
  }

  union UU { bf16x8 v8; bf16x4 v4[2]; };
  UU a1, a2;
  {
    const int dbase = h * 2048 + u * 128;
    const int sw = (u & 7) << 3;
    a1.v4[0] = *(const bf16x4*)((char*)vT + dbase + ((8 * g) ^ sw));
    a1.v4[1] = *(const bf16x4*)((char*)vT + dbase + ((32 + 8 * g) ^ sw));
    a2.v4[0] = *(const bf16x4*)((char*)vT + dbase + ((64 + 8 * g) ^ sw));
    a2.v4[1] = *(const bf16x4*)((char*)vT + dbase + ((96 + 8 * g) ^ sw));
  }
#pragma unroll
  for (int qt = 0; qt < 3; qt++) {
    UU bu1, bu2;
#pragma unroll
    for (int i = 0; i < 4; i++) {
      bu1.v8[i] = f2bf(d1[0][qt][i]);
      bu1.v8[i + 4] = f2bf(d1[1][qt][i]);
      bu2.v8[i] = f2bf(d1[2][qt][i]);
      bu2.v8[i + 4] = 0;
    }
    f32x4 z = {0.f, 0.f, 0.f, 0.f};
    f32x4 acc = MFMA(a1.v8, bu1.v8, z);
    acc = MFMA(a2.v8, bu2.v8, acc);  // o^T[d][q]
#pragma unroll
    for (int reg = 0; reg < 4; reg++)
      o_lds[(qt * 16 + u) * 128 + h * 16 + 4 * g + reg] = f2bf(acc[reg] * rl[qt]);
  }
  __syncthreads();
  for (int idx = t; idx < 768; idx += 512) {
    int r = idx >> 4, c8 = idx & 15;
    if (canon_s[r]) {
      *(bf16x8*)(ocmp + (size_t)midx_s[r] * 128 + c8 * 8) =
          *(const bf16x8*)(o_lds + r * 128 + c8 * 8);
    }
  }
}

// --------------------- K3: proj GEMM + atomic segment-sum ------------------
__global__ __launch_bounds__(256) void k3_proj(
    const short* __restrict__ ocmp, const short* __restrict__ wp,
    const float* __restrict__ pb, const int* __restrict__ pinv,
    float* __restrict__ dout, int M) {
  __shared__ short a_lds[64 * 128];
  __shared__ int nidx[64];
  const int blk = blockIdx.x, t = threadIdx.x;
  const int m0 = blk * 64;
  {
    const int r = t >> 2, quad = t & 3;
    const int m = m0 + r;
    if (quad == 0) nidx[r] = (m < M) ? pinv[m] : 0;
    if (m < M) {
      const char* src = (const char*)(ocmp + (size_t)m * 128);
#pragma unroll
      for (int i = 0; i < 4; i++) {
        int boff = quad * 64 + i * 16;
        *(bf16x8*)((char*)a_lds + r * 256 + (boff ^ ((r & 7) << 4))) =
            *(const bf16x8*)(src + boff);
      }
    } else {
      bf16x8 z = {0, 0, 0, 0, 0, 0, 0, 0};
#pragma unroll
      for (int i = 0; i < 4; i++) {
        int boff = quad * 64 + i * 16;
        *(bf16x8*)((char*)a_lds + r * 256 + (boff ^ ((r & 7) << 4))) = z;
      }
    }
  }
  __syncthreads();
  const int wave = t >> 6, lane = t & 63, u = lane & 15, g = lane >> 4;
  f32x4 acc[4][2];
  f32x4 zz = {0.f, 0.f, 0.f, 0.f};
#pragma unroll
  for (int a = 0; a < 4; a++) { acc[a][0] = zz; acc[a][1] = zz; }
#pragma unroll
  for (int kk = 0; kk < 4; kk++) {
    bf16x8 af[4];
#pragma unroll
    for (int rt = 0; rt < 4; rt++)
      af[rt] = *(const bf16x8*)((char*)a_lds + (rt * 16 + u) * 256 +
                                ((kk * 64 + g * 16) ^ ((u & 7) << 4)));
    bf16x8 bfr[2];
#pragma unroll
    for (int ct = 0; ct < 2; ct++) {
      int col = wave * 32 + ct * 16 + u;
      bfr[ct] = *(const bf16x8*)(wp + (size_t)col * 128 + kk * 32 + g * 8);
    }
#pragma unroll
    for (int rt = 0; rt < 4; rt++)
#pragma unroll
      for (int ct = 0; ct < 2; ct++) acc[rt][ct] = MFMA(af[rt], bfr[ct], acc[rt][ct]);
  }
#pragma unroll
  for (int rt = 0; rt < 4; rt++)
#pragma unroll
    for (int ct = 0; ct < 2; ct++) {
      int col = wave * 32 + ct * 16 + u;
      float bias = pb[col];
#pragma unroll
      for (int reg = 0; reg < 4; reg++) {
        int ml = rt * 16 + 4 * g + reg;
        if (m0 + ml < M)
          atomicAdd(dout + (size_t)nidx[ml] * 128 + col, acc[rt][ct][reg] + bias);
      }
    }
}

// ------- K4b: x = feat + sums/cnt (in-place in d_out); LN2; fc1+GELU -------
__global__ __launch_bounds__(256) void k4b_x_ln_fc1(
    const float* __restrict__ feat, float* __restrict__ dout,
    const float* __restrict__ cnt, const float* __restrict__ g2,
    const float* __restrict__ b2, const short* __restrict__ w1,
    const float* __restrict__ bb1, short* __restrict__ mact) {
  __shared__ short h_lds[64 * 128];
  __shared__ short o_st[64 * 512];
  const int blk = blockIdx.x, t = threadIdx.x;
  {
    const int r = t >> 2, quad = t & 3;
    const size_t row = (size_t)blk * 64 + r;
    const float* fp = feat + row * 128 + quad * 32;
    float* xp = dout + row * 128 + quad * 32;
    float rc = 1.0f / fmaxf(cnt[row], 1.0f);
    float vals[32];
    float s = 0.f, s2 = 0.f;
#pragma unroll
    for (int i = 0; i < 8; i++) {
      f32x4 fv = *(const f32x4*)(fp + i * 4);
      f32x4 sv = *(const f32x4*)(xp + i * 4);
      f32x4 xv;
#pragma unroll
      for (int j = 0; j < 4; j++) {
        float x = fv[j] + sv[j] * rc;
        xv[j] = x; vals[i * 4 + j] = x; s += x; s2 += x * x;
      }
      *(f32x4*)(xp + i * 4) = xv;
    }
    s += __shfl_xor(s, 1);  s += __shfl_xor(s, 2);
    s2 += __shfl_xor(s2, 1); s2 += __shfl_xor(s2, 2);
    float mean = s * (1.f / 128.f);
    float rstd = rsqrtf(s2 * (1.f / 128.f) - mean * mean + 1e-5f);
    const int sw = (r & 7) << 4;
#pragma unroll
    for (int gi = 0; gi < 4; gi++) {
      bf16x8 wv;
#pragma unroll
      for (int j = 0; j < 8; j++) {
        int c = quad * 32 + gi * 8 + j;
        wv[j] = f2bf((vals[gi * 8 + j] - mean) * rstd * g2[c] + b2[c]);
      }
      *(bf16x8*)((char*)h_lds + r * 256 + ((quad * 64 + gi * 16) ^ sw)) = wv;
    }
  }
  __syncthreads();
  const int wave = t >> 6, lane = t & 63, u = lane & 15, g = lane >> 4;
  f32x4 acc[4][8];
  f32x4 zz = {0.f, 0.f, 0.f, 0.f};
#pragma unroll
  for (int a = 0; a < 4; a++)
#pragma unroll
    for (int b = 0; b < 8; b++) acc[a][b] = zz;
#pragma unroll
  for (int kk = 0; kk < 4; kk++) {
    bf16x8 af[4];
#pragma unroll
    for (int rt = 0; rt < 4; rt++)
      af[rt] = *(const bf16x8*)((char*)h_lds + (rt * 16 + u) * 256 +
                                ((kk * 64 + g * 16) ^ ((u & 7) << 4)));
    bf16x8 bfr[8];
#pragma unroll
    for (int ct = 0; ct < 8; ct++) {
      int col = wave * 128 + ct * 16 + u;
      bfr[ct] = *(const bf16x8*)(w1 + (size_t)col * 128 + kk * 32 + g * 8);
    }
#pragma unroll
    for (int rt = 0; rt < 4; rt++)
#pragma unroll
      for (int ct = 0; ct < 8; ct++) acc[rt][ct] = MFMA(af[rt], bfr[ct], acc[rt][ct]);
  }
#pragma unroll
  for (int rt = 0; rt < 4; rt++)
#pragma unroll
    for (int ct = 0; ct < 8; ct++) {
      int col = wave * 128 + ct * 16 + u;
      float bias = bb1[col];
#pragma unroll
      for (int reg = 0; reg < 4; reg++) {
        int rowl = rt * 16 + 4 * g + reg;
        float v = acc[rt][ct][reg] + bias;
        v = 0.5f * v * (1.0f + erff(v * 0.70710678118654752f));  // exact GELU
        o_st[rowl * 512 + col] = f2bf(v);
      }
    }
  __syncthreads();
  for (int idx = t; idx < 4096; idx += 256) {
    int rr = idx >> 6, c8 = idx & 63;
    *(bf16x8*)(mact + ((size_t)blk * 64 + rr) * 512 + c8 * 8) =
        *(const bf16x8*)(o_st + rr * 512 + c8 * 8);
  }
}

// --------------------- K4c: fc2 + residual into d_out ----------------------
__global__ __launch_bounds__(256) void k4c_fc2(
    const short* __restrict__ mact, const short* __restrict__ w2,
    const float* __restrict__ bb2, float* __restrict__ dout) {
  __shared__ short a_lds[64 * 512];
  const int blk = blockIdx.x, t = threadIdx.x;
  {
    const int r = t >> 2, quad = t & 3;
    const size_t row = (size_t)blk * 64 + r;
    const char* src = (const char*)(mact + row * 512);
#pragma unroll
    for (int i = 0; i < 16; i++) {
      int boff = quad * 256 + i * 16;
      *(bf16x8*)((char*)a_lds + r * 1024 + (boff ^ ((r & 7) << 4))) =
          *(const bf16x8*)(src + boff);
    }
  }
  __syncthreads();
  const int wave = t >> 6, lane = t & 63, u = lane & 15, g = lane >> 4;
  f32x4 acc[8];
  f32x4 zz = {0.f, 0.f, 0.f, 0.f};
#pragma unroll
  for (int a = 0; a < 8; a++) acc[a] = zz;
  const int rowl = wave * 16 + u;
#pragma unroll
  for (int kk = 0; kk < 16; kk++) {
    bf16x8 af = *(const bf16x8*)((char*)a_lds + rowl * 1024 +
                                 ((kk * 64 + g * 16) ^ ((u & 7) << 4)));
#pragma unroll
    for (int ct = 0; ct < 8; ct++) {
      int col = ct * 16 + u;
      bf16x8 bfr = *(const bf16x8*)(w2 + (size_t)col * 512 + kk * 32 + g * 8);
      acc[ct] = MFMA(af, bfr, acc[ct]);
    }
  }
#pragma unroll
  for (int ct = 0; ct < 8; ct++) {
    int col = ct * 16 + u;
    float bias = bb2[col];
#pragma unroll
    for (int reg = 0; reg < 4; reg++) {
      size_t rr = (size_t)blk * 64 + wave * 16 + 4 * g + reg;
      float* p = dout + rr * 128 + col;
      *p = *p + acc[ct][reg] + bias;
    }
  }
}

// ---------------------------------------------------------------------------
extern "C" void kernel_launch(void* const* d_in, const int* in_sizes, int n_in,
                              void* d_out, int out_size, void* d_ws, size_t ws_size,
                              hipStream_t stream) {
  (void)n_in; (void)out_size; (void)ws_size;
  const float* feat   = (const float*)d_in[0];
  const float* cosb   = (const float*)d_in[1];
  const float* sinb   = (const float*)d_in[2];
  const float* g1     = (const float*)d_in[3];
  const float* b1     = (const float*)d_in[4];
  const float* qkv_w  = (const float*)d_in[5];
  const float* qkv_b  = (const float*)d_in[6];
  const float* proj_w = (const float*)d_in[7];
  const float* proj_b = (const float*)d_in[8];
  const float* g2     = (const float*)d_in[9];
  const float* b2     = (const float*)d_in[10];
  const float* fc1_w  = (const float*)d_in[11];
  const float* fc1_b  = (const float*)d_in[12];
  const float* fc2_w  = (const float*)d_in[13];
  const float* fc2_b  = (const float*)d_in[14];
  const int* pinv     = (const int*)d_in[15];
  const int* padv     = (const int*)d_in[16];
  const int* unpadv   = (const int*)d_in[17];

  const int N    = in_sizes[0] / 128;
  const int M    = in_sizes[15];
  const int Mpad = in_sizes[16];
  const int Wn   = Mpad / 48;

  float* dout = (float*)d_out;
  char* ws = (char*)d_ws;

  // ws layout (bytes):
  //  [0, N*384*2)                      qkv bf16        (dead after K2)
  //  [N*384*2, +M*128*2)               o_cmp bf16      (dead after K3)
  //  [0, N*512*2)                      mact bf16       (reuses qkv+ocmp space)
  //  then cnt (N*4), then bf16 weights (393216 B). Total ~175 MB.
  size_t offQ = 0;
  size_t szQ = (size_t)N * 384 * 2;
  size_t offO = offQ + szQ;
  size_t szO = (size_t)M * 128 * 2;
  size_t offC = offO + szO;
  size_t offW = offC + (size_t)N * 4;

  short* qkvb = (short*)(ws + offQ);
  short* ocmp = (short*)(ws + offO);
  short* mact = (short*)(ws + offQ);  // overlaps qkv/ocmp (both dead by K4b)
  float* cnt  = (float*)(ws + offC);
  short* wq_b = (short*)(ws + offW);
  short* wp_b = wq_b + 49152;
  short* w1_b = wp_b + 16384;
  short* w2_b = w1_b + 65536;

  hipMemsetAsync(dout, 0, (size_t)N * 128 * 4, stream);
  hipMemsetAsync(cnt, 0, (size_t)N * 4, stream);

  k_cvt<<<(49152 + 255) / 256, 256, 0, stream>>>(qkv_w, wq_b, 49152);
  k_cvt<<<(16384 + 255) / 256, 256, 0, stream>>>(proj_w, wp_b, 16384);
  k_cvt<<<(65536 + 255) / 256, 256, 0, stream>>>(fc1_w, w1_b, 65536);
  k_cvt<<<(65536 + 255) / 256, 256, 0, stream>>>(fc2_w, w2_b, 65536);

  k1_ln_qkv<<<N / 64, 256, 0, stream>>>(feat, g1, b1, wq_b, qkv_b, qkvb);
  k_cnt<<<(M + 255) / 256, 256, 0, stream>>>(pinv, cnt, M);
  k2_attn<<<Wn, 512, 0, stream>>>(qkvb, cosb, sinb, pinv, padv, unpadv, ocmp);
  k3_proj<<<(M + 63) / 64, 256, 0, stream>>>(ocmp, wp_b, proj_b, pinv, dout, M);
  k4b_x_ln_fc1<<<N / 64, 256, 0, stream>>>(feat, dout, cnt, g2, b2, w1_b, fc1_b, mact);
  k4c_fc2<<<N / 64, 256, 0, stream>>>(mact, w2_b, fc2_b, dout);
}